// Round 1
// baseline (9998.547 us; speedup 1.0000x reference)
//
#include <hip/hip_runtime.h>

// Decoder: 2-layer LSTM, B=1024, IN=256, H=512, OUT=256, T2=128 (hardcoded).
// Strategy: bf16 MFMA (32x32x16) for all matmuls, fp32 accumulate, fp32 cell
// state + activations. 3 kernels per step: cell0, cell1, fc(+lin fused).
// Weights converted to bf16 once per launch (ws is re-poisoned each call).

typedef __attribute__((ext_vector_type(8))) __bf16 bf16x8;
typedef __attribute__((ext_vector_type(16))) float f32x16;

__device__ __forceinline__ f32x16 mfma_bf16(bf16x8 a, bf16x8 b, f32x16 c) {
  return __builtin_amdgcn_mfma_f32_32x32x16_bf16(a, b, c, 0, 0, 0);
}

__device__ __forceinline__ short f2bf(float f) {  // RNE fp32->bf16 (bit pattern)
  unsigned u = __float_as_uint(f);
  u += 0x7fffu + ((u >> 16) & 1u);
  return (short)(u >> 16);
}

__device__ __forceinline__ float sigm(float x) { return 1.0f / (1.0f + __expf(-x)); }
__device__ __forceinline__ float tanh_fast(float x) { return 2.0f / (1.0f + __expf(-2.0f * x)) - 1.0f; }

__device__ __forceinline__ f32x16 zero16() {
  f32x16 z;
#pragma unroll
  for (int i = 0; i < 16; ++i) z[i] = 0.0f;
  return z;
}

// ---------------------------------------------------------------------------
// prep: bf16-convert weights (concat [W_ih|W_hh]), sum biases, init states.
// ---------------------------------------------------------------------------
__global__ __launch_bounds__(256) void prep_kernel(
    const float* __restrict__ z0, const float* __restrict__ h0in, const float* __restrict__ c0in,
    const float* __restrict__ Wih0, const float* __restrict__ Whh0,
    const float* __restrict__ bih0, const float* __restrict__ bhh0,
    const float* __restrict__ Wih1, const float* __restrict__ Whh1,
    const float* __restrict__ bih1, const float* __restrict__ bhh1,
    const float* __restrict__ fcW, const float* __restrict__ linW,
    short* __restrict__ wcat0, short* __restrict__ wcat1,
    short* __restrict__ fcWb, short* __restrict__ linWb,
    float* __restrict__ bias0, float* __restrict__ bias1,
    short* __restrict__ zbuf, short* __restrict__ h0b, short* __restrict__ h1b,
    float* __restrict__ c0, float* __restrict__ c1)
{
  int idx = blockIdx.x * 256 + threadIdx.x;
  if (idx < 1572864) {  // wcat0 [2048][768] = [W_ih0 | W_hh0]
    int r = idx / 768, cc = idx % 768;
    wcat0[idx] = f2bf(cc < 256 ? Wih0[r * 256 + cc] : Whh0[r * 512 + cc - 256]);
    return;
  }
  idx -= 1572864;
  if (idx < 2097152) {  // wcat1 [2048][1024] = [W_ih1 | W_hh1]
    int r = idx >> 10, cc = idx & 1023;
    wcat1[idx] = f2bf(cc < 512 ? Wih1[(r << 9) + cc] : Whh1[(r << 9) + cc - 512]);
    return;
  }
  idx -= 2097152;
  if (idx < 131072) { fcWb[idx] = f2bf(fcW[idx]); return; }
  idx -= 131072;
  if (idx < 65536) { linWb[idx] = f2bf(linW[idx]); return; }
  idx -= 65536;
  if (idx < 2048) { bias0[idx] = bih0[idx] + bhh0[idx]; return; }
  idx -= 2048;
  if (idx < 2048) { bias1[idx] = bih1[idx] + bhh1[idx]; return; }
  idx -= 2048;
  if (idx < 262144) { zbuf[idx] = f2bf(z0[idx]); return; }
  idx -= 262144;
  if (idx < 524288) { h0b[idx] = f2bf(h0in[idx]); return; }
  idx -= 524288;
  if (idx < 524288) { h1b[idx] = f2bf(h0in[524288 + idx]); return; }
  idx -= 524288;
  if (idx < 524288) { c0[idx] = c0in[idx]; return; }
  idx -= 524288;
  if (idx < 524288) { c1[idx] = c0in[524288 + idx]; return; }
}

// ---------------------------------------------------------------------------
// cell: gates = [x | h] @ Wcat^T + bias, then LSTM cell. Writes h_next (bf16)
// and c in place (fp32). Block = [64 batch rows x 32 hidden x 4 gates],
// 256 thr (wave w owns gate w). Grid (16,16) = 256 blocks = 1/CU.
// LDS fragment layout [k/8][m][8] so ds_read_b128 hits the bank floor.
// ---------------------------------------------------------------------------
template <int K, int KX>
__global__ __launch_bounds__(256) void cell_kernel(
    const short* __restrict__ xbuf, int ldx,
    const short* __restrict__ hbuf,        // stride 512
    const short* __restrict__ Wcat,        // [2048][K] bf16
    const float* __restrict__ bias,        // [2048]
    float* __restrict__ c,                 // [1024][512]
    short* __restrict__ hout)              // [1024][512] bf16
{
  __shared__ __align__(16) short At[8 * 64 * 8];       // [ks8][m64][8]  8 KB
  __shared__ __align__(16) short Bt[4 * 8 * 32 * 8];   // [g4][ks8][n32][8] 16 KB
  __shared__ __align__(16) float gbuf[4 * 64 * 32];    // [g][m][n] 32 KB

  const int t = threadIdx.x;
  const int w = t >> 6;        // wave = gate
  const int l = t & 63;
  const int half = l >> 5;
  const int ln = l & 31;
  const int j0 = blockIdx.x * 32;    // hidden base
  const int row0 = blockIdx.y * 64;  // batch base

  const int sks = (t >> 3) & 7;            // staging k-group 0..7
  const int sm = (t & 7) + 8 * (t >> 6);   // staging row 0..31

  f32x16 acc0 = zero16();
  f32x16 acc1 = zero16();

  for (int kt = 0; kt < K / 64; ++kt) {
    __syncthreads();
    {  // stage A (x or h source; K-tiles never straddle since KX%64==0)
      const int kc = kt * 64;
      const short* src; int ld, col;
      if (kc < KX) { src = xbuf; ld = ldx; col = kc; }
      else         { src = hbuf; ld = 512; col = kc - KX; }
#pragma unroll
      for (int i = 0; i < 2; ++i) {
        const int m = sm + i * 32;
        *(uint4*)&At[(sks * 64 + m) * 8] =
            *(const uint4*)&src[(row0 + m) * ld + col + sks * 8];
      }
    }
#pragma unroll
    for (int g = 0; g < 4; ++g) {  // stage B: W rows g*512 + j0 + n
      *(uint4*)&Bt[((g * 8 + sks) * 32 + sm) * 8] =
          *(const uint4*)&Wcat[(g * 512 + j0 + sm) * K + kt * 64 + sks * 8];
    }
    __syncthreads();
#pragma unroll
    for (int s = 0; s < 4; ++s) {  // 4 x K16 steps
      const bf16x8 a0 = *(const bf16x8*)&At[((2 * s + half) * 64 + ln) * 8];
      const bf16x8 a1 = *(const bf16x8*)&At[((2 * s + half) * 64 + 32 + ln) * 8];
      const bf16x8 b  = *(const bf16x8*)&Bt[((w * 8 + 2 * s + half) * 32 + ln) * 8];
      acc0 = mfma_bf16(a0, b, acc0);
      acc1 = mfma_bf16(a1, b, acc1);
    }
  }

  // C layout (verified m74/m101): col = lane&31, row = (r&3)+8*(r>>2)+4*(lane>>5)
#pragma unroll
  for (int r = 0; r < 16; ++r) {
    const int mloc = (r & 3) + 8 * (r >> 2) + 4 * half;
    gbuf[(w * 64 + mloc) * 32 + ln] = acc0[r];
    gbuf[(w * 64 + mloc + 32) * 32 + ln] = acc1[r];
  }
  __syncthreads();

  {  // elementwise cell: thread t -> m = t>>2, n = (t&3)*8 .. +7
    const int m = t >> 2;
    const int nb = (t & 3) * 8;
    const int grow = row0 + m;
    short htmp[8];
#pragma unroll
    for (int u = 0; u < 8; ++u) {
      const int n = nb + u;
      const int jn = j0 + n;
      const float gi = gbuf[(0 * 64 + m) * 32 + n] + bias[jn];
      const float gf = gbuf[(1 * 64 + m) * 32 + n] + bias[512 + jn];
      const float gg = gbuf[(2 * 64 + m) * 32 + n] + bias[1024 + jn];
      const float go = gbuf[(3 * 64 + m) * 32 + n] + bias[1536 + jn];
      const float cold = c[grow * 512 + jn];
      const float iv = sigm(gi);
      const float fv = sigm(gf);
      const float gv = tanh_fast(gg);
      const float ov = sigm(go);
      const float cn = fv * cold + iv * gv;
      const float hn = ov * tanh_fast(cn);
      c[grow * 512 + jn] = cn;
      htmp[u] = f2bf(hn);
    }
    *(uint4*)&hout[grow * 512 + j0 + nb] = *(uint4*)htmp;
  }
}

// ---------------------------------------------------------------------------
// fc+lin fused: z = h1 @ fcW^T + fc_b (bf16 -> zbuf + LDS), then
// out_t = z @ linW^T + lin_b (fp32 -> d_out). Block owns all 256 z-cols so
// lin's K=256 reduction is block-local. Grid = 16 blocks (M=1024/64).
// ---------------------------------------------------------------------------
__global__ __launch_bounds__(256) void fc_kernel(
    const short* __restrict__ h1,     // [1024][512] bf16
    const short* __restrict__ fcWb,   // [256][512] bf16
    const short* __restrict__ linWb,  // [256][256] bf16
    const float* __restrict__ fcb, const float* __restrict__ linb,
    short* __restrict__ zbuf,         // [1024][256] bf16
    float* __restrict__ outp)         // [1024][256] fp32 (this step's slice)
{
  __shared__ __align__(16) short At[4 * 64 * 8];    // 4 KB
  __shared__ __align__(16) short Bt[4 * 256 * 8];   // 16 KB
  __shared__ __align__(16) short Zt[32 * 64 * 8];   // [k/8][m][8] 32 KB

  const int t = threadIdx.x;
  const int w = t >> 6;
  const int l = t & 63;
  const int half = l >> 5;
  const int ln = l & 31;
  const int row0 = blockIdx.x * 64;

  const int sks = (t >> 3) & 3;            // 0..3
  const int sm = (t & 7) + 8 * (t >> 5);   // 0..63

  f32x16 acc[2][2] = {zero16(), zero16(), zero16(), zero16()};

  for (int kt = 0; kt < 16; ++kt) {  // K = 512, Ktile = 32
    __syncthreads();
    *(uint4*)&At[(sks * 64 + sm) * 8] =
        *(const uint4*)&h1[(row0 + sm) * 512 + kt * 32 + sks * 8];
#pragma unroll
    for (int i = 0; i < 4; ++i) {
      const int n = i * 64 + sm;
      *(uint4*)&Bt[(sks * 256 + n) * 8] =
          *(const uint4*)&fcWb[n * 512 + kt * 32 + sks * 8];
    }
    __syncthreads();
#pragma unroll
    for (int s = 0; s < 2; ++s) {
      const bf16x8 a0 = *(const bf16x8*)&At[((2 * s + half) * 64 + ln) * 8];
      const bf16x8 a1 = *(const bf16x8*)&At[((2 * s + half) * 64 + 32 + ln) * 8];
      const bf16x8 b0 = *(const bf16x8*)&Bt[((2 * s + half) * 256 + w * 64 + ln) * 8];
      const bf16x8 b1 = *(const bf16x8*)&Bt[((2 * s + half) * 256 + w * 64 + 32 + ln) * 8];
      acc[0][0] = mfma_bf16(a0, b0, acc[0][0]);
      acc[0][1] = mfma_bf16(a0, b1, acc[0][1]);
      acc[1][0] = mfma_bf16(a1, b0, acc[1][0]);
      acc[1][1] = mfma_bf16(a1, b1, acc[1][1]);
    }
  }

  // z -> bf16 -> Zt (A-frag layout for stage 2)
#pragma unroll
  for (int mt = 0; mt < 2; ++mt) {
#pragma unroll
    for (int nt = 0; nt < 2; ++nt) {
      const int n = w * 64 + nt * 32 + ln;
      const float bv = fcb[n];
#pragma unroll
      for (int r = 0; r < 16; ++r) {
        const int m = (r & 3) + 8 * (r >> 2) + 4 * half + mt * 32;
        Zt[((n >> 3) * 64 + m) * 8 + (n & 7)] = f2bf(acc[mt][nt][r] + bv);
      }
    }
  }
  __syncthreads();
  // Zt -> zbuf (coalesced 16B)
#pragma unroll
  for (int i = 0; i < 8; ++i) {
    const int cidx = i * 256 + t;
    const int m = cidx >> 5;
    const int ng = cidx & 31;
    *(uint4*)&zbuf[(row0 + m) * 256 + ng * 8] = *(uint4*)&Zt[(ng * 64 + m) * 8];
  }

  // stage 2: out = z @ linW^T + lin_b, K = 256
  f32x16 o[2][2] = {zero16(), zero16(), zero16(), zero16()};
  for (int kt = 0; kt < 8; ++kt) {
    __syncthreads();
#pragma unroll
    for (int i = 0; i < 4; ++i) {
      const int n = i * 64 + sm;
      *(uint4*)&Bt[(sks * 256 + n) * 8] =
          *(const uint4*)&linWb[n * 256 + kt * 32 + sks * 8];
    }
    __syncthreads();
#pragma unroll
    for (int s = 0; s < 2; ++s) {
      const int ksg = kt * 4 + 2 * s + half;
      const bf16x8 a0 = *(const bf16x8*)&Zt[(ksg * 64 + ln) * 8];
      const bf16x8 a1 = *(const bf16x8*)&Zt[(ksg * 64 + 32 + ln) * 8];
      const bf16x8 b0 = *(const bf16x8*)&Bt[((2 * s + half) * 256 + w * 64 + ln) * 8];
      const bf16x8 b1 = *(const bf16x8*)&Bt[((2 * s + half) * 256 + w * 64 + 32 + ln) * 8];
      o[0][0] = mfma_bf16(a0, b0, o[0][0]);
      o[0][1] = mfma_bf16(a0, b1, o[0][1]);
      o[1][0] = mfma_bf16(a1, b0, o[1][0]);
      o[1][1] = mfma_bf16(a1, b1, o[1][1]);
    }
  }
#pragma unroll
  for (int mt = 0; mt < 2; ++mt) {
#pragma unroll
    for (int nt = 0; nt < 2; ++nt) {
      const int n = w * 64 + nt * 32 + ln;
      const float bv = linb[n];
#pragma unroll
      for (int r = 0; r < 16; ++r) {
        const int m = (r & 3) + 8 * (r >> 2) + 4 * half + mt * 32;
        outp[(row0 + m) * 256 + n] = o[mt][nt][r] + bv;
      }
    }
  }
}

// ---------------------------------------------------------------------------
extern "C" void kernel_launch(void* const* d_in, const int* in_sizes, int n_in,
                              void* d_out, int out_size, void* d_ws, size_t ws_size,
                              hipStream_t stream) {
  const float* z0   = (const float*)d_in[0];
  const float* h0in = (const float*)d_in[1];
  const float* c0in = (const float*)d_in[2];
  const float* Wih0 = (const float*)d_in[3];
  const float* Whh0 = (const float*)d_in[4];
  const float* bih0 = (const float*)d_in[5];
  const float* bhh0 = (const float*)d_in[6];
  const float* Wih1 = (const float*)d_in[7];
  const float* Whh1 = (const float*)d_in[8];
  const float* bih1 = (const float*)d_in[9];
  const float* bhh1 = (const float*)d_in[10];
  const float* fcW  = (const float*)d_in[11];
  const float* fcb  = (const float*)d_in[12];
  const float* linW = (const float*)d_in[13];
  const float* linb = (const float*)d_in[14];
  float* out = (float*)d_out;

  char* ws = (char*)d_ws;
  short* wcat0 = (short*)(ws + 0);         // 3,145,728 B
  short* wcat1 = (short*)(ws + 3145728);   // 4,194,304 B
  short* fcWb  = (short*)(ws + 7340032);   //   262,144 B
  short* linWb = (short*)(ws + 7602176);   //   131,072 B
  float* bias0 = (float*)(ws + 7733248);   //     8,192 B
  float* bias1 = (float*)(ws + 7741440);   //     8,192 B
  short* zbuf  = (short*)(ws + 7749632);   //   524,288 B
  short* h0b0  = (short*)(ws + 8273920);   // 1,048,576 B
  short* h0b1  = (short*)(ws + 9322496);
  short* h1b0  = (short*)(ws + 10371072);
  short* h1b1  = (short*)(ws + 11419648);
  float* c0    = (float*)(ws + 12468224);  // 2,097,152 B
  float* c1    = (float*)(ws + 14565376);  // total 16,662,528 B
  short* h0b[2] = {h0b0, h0b1};
  short* h1b[2] = {h1b0, h1b1};

  prep_kernel<<<24336, 256, 0, stream>>>(z0, h0in, c0in, Wih0, Whh0, bih0, bhh0,
                                         Wih1, Whh1, bih1, bhh1, fcW, linW,
                                         wcat0, wcat1, fcWb, linWb, bias0, bias1,
                                         zbuf, h0b0, h1b0, c0, c1);

  dim3 cgrid(16, 16);
  for (int t = 0; t < 128; ++t) {  // T2 = 128
    const int cur = t & 1, nxt = cur ^ 1;
    cell_kernel<768, 256><<<cgrid, 256, 0, stream>>>(zbuf, 256, h0b[cur], wcat0,
                                                     bias0, c0, h0b[nxt]);
    cell_kernel<1024, 512><<<cgrid, 256, 0, stream>>>(h0b[nxt], 512, h1b[cur], wcat1,
                                                      bias1, c1, h1b[nxt]);
    fc_kernel<<<16, 256, 0, stream>>>(h1b[nxt], fcWb, linWb, fcb, linb, zbuf,
                                      out + (size_t)t * 262144);
  }
}

// Round 2
// 9778.837 us; speedup vs baseline: 1.0225x; 1.0225x over previous
//
#include <hip/hip_runtime.h>

// Decoder: 2-layer LSTM, B=1024, IN=256, H=512, OUT=256, T2=128 (hardcoded).
// PERSISTENT-KERNEL design: 256 blocks x 512 thr, resident for all 128 steps.
// 16 groups (64 batch rows) x 16 blocks (32-hidden j-slice). Group-local
// 16-block barriers (agent-scope atomics). Weights pre-swizzled to MFMA
// B-frag order, read straight from L2 (XCD-affinity blockIdx swizzle).
// h/z exchanged via agent-scope (sc1) b64 atomic loads/stores => coherent
// through L3 without buffer_inv (weight L2 residency preserved).
// c-state lives in VGPRs for the whole kernel.

typedef __attribute__((ext_vector_type(8))) __bf16 bf16x8;
typedef __attribute__((ext_vector_type(16))) float f32x16;
typedef unsigned long long ull;

__device__ __forceinline__ f32x16 mfma_bf16(bf16x8 a, bf16x8 b, f32x16 c) {
  return __builtin_amdgcn_mfma_f32_32x32x16_bf16(a, b, c, 0, 0, 0);
}

__device__ __forceinline__ short f2bf(float f) {  // RNE fp32->bf16
  unsigned u = __float_as_uint(f);
  u += 0x7fffu + ((u >> 16) & 1u);
  return (short)(u >> 16);
}

__device__ __forceinline__ float sigm(float x) { return 1.0f / (1.0f + __expf(-x)); }
__device__ __forceinline__ float tanh_fast(float x) { return 2.0f / (1.0f + __expf(-2.0f * x)) - 1.0f; }

__device__ __forceinline__ f32x16 zero16() {
  f32x16 z;
#pragma unroll
  for (int i = 0; i < 16; ++i) z[i] = 0.0f;
  return z;
}

// ---------------------------------------------------------------------------
// prep: swizzle weights into per-(block, k16-step, gate) lane-contiguous MFMA
// B-fragments; sum biases; init bf16 states; zero barrier flags.
// ---------------------------------------------------------------------------
__global__ __launch_bounds__(256) void prep_kernel(
    const float* __restrict__ z0, const float* __restrict__ h0in,
    const float* __restrict__ Wih0, const float* __restrict__ Whh0,
    const float* __restrict__ bih0, const float* __restrict__ bhh0,
    const float* __restrict__ Wih1, const float* __restrict__ Whh1,
    const float* __restrict__ bih1, const float* __restrict__ bhh1,
    const float* __restrict__ fcW, const float* __restrict__ linW,
    short* __restrict__ wsw0, short* __restrict__ wsw1,
    short* __restrict__ fcWsw, short* __restrict__ linWsw,
    float* __restrict__ bias0, float* __restrict__ bias1,
    short* __restrict__ zb1, short* __restrict__ h0b0, short* __restrict__ h1b0,
    int* __restrict__ flags)
{
  int idx = blockIdx.x * 256 + threadIdx.x;
  if (idx < 1572864) {  // wsw0 [b16][s48][g4][l64][j8]; K=768 = [z 256 | h0 512]
    int jj = idx & 7, l = (idx >> 3) & 63, gg = (idx >> 9) & 3;
    int rest = idx >> 11;           // b*48 + s
    int s = rest % 48, b = rest / 48;
    int row = gg * 512 + b * 32 + (l & 31);
    int k = s * 16 + (l >> 5) * 8 + jj;
    wsw0[idx] = f2bf(k < 256 ? Wih0[row * 256 + k] : Whh0[row * 512 + (k - 256)]);
    return;
  }
  idx -= 1572864;
  if (idx < 2097152) {  // wsw1 [b16][s64][g4][l64][j8]; K=1024 = [h0 512 | h1 512]
    int jj = idx & 7, l = (idx >> 3) & 63, gg = (idx >> 9) & 3;
    int rest = idx >> 11;           // b*64 + s
    int s = rest & 63, b = rest >> 6;
    int row = gg * 512 + b * 32 + (l & 31);
    int k = s * 16 + (l >> 5) * 8 + jj;
    wsw1[idx] = f2bf(k < 512 ? Wih1[row * 512 + k] : Whh1[row * 512 + (k - 512)]);
    return;
  }
  idx -= 2097152;
  if (idx < 131072) {  // fcWsw [jz8][s32][l64][j8]; N-slice 32, K=512
    int jj = idx & 7, l = (idx >> 3) & 63, s = (idx >> 9) & 31, jz = idx >> 14;
    int col = jz * 32 + (l & 31);
    int k = s * 16 + (l >> 5) * 8 + jj;
    fcWsw[idx] = f2bf(fcW[col * 512 + k]);
    return;
  }
  idx -= 131072;
  if (idx < 65536) {  // linWsw [jo8][s16][l64][j8]; N-slice 32, K=256
    int jj = idx & 7, l = (idx >> 3) & 63, s = (idx >> 9) & 15, jo = idx >> 13;
    int col = jo * 32 + (l & 31);
    int k = s * 16 + (l >> 5) * 8 + jj;
    linWsw[idx] = f2bf(linW[col * 256 + k]);
    return;
  }
  idx -= 65536;
  if (idx < 2048) { bias0[idx] = bih0[idx] + bhh0[idx]; return; }
  idx -= 2048;
  if (idx < 2048) { bias1[idx] = bih1[idx] + bhh1[idx]; return; }
  idx -= 2048;
  if (idx < 262144) { zb1[idx] = f2bf(z0[idx]); return; }
  idx -= 262144;
  if (idx < 524288) { h0b0[idx] = f2bf(h0in[idx]); return; }
  idx -= 524288;
  if (idx < 524288) { h1b0[idx] = f2bf(h0in[524288 + idx]); return; }
  idx -= 524288;
  if (idx < 6144) { flags[idx] = 0; return; }
}

// ---------------------------------------------------------------------------
// persistent kernel helpers
// ---------------------------------------------------------------------------
__device__ __forceinline__ void group_barrier(int* f) {
  __builtin_amdgcn_s_waitcnt(0);   // every thread drains its own sc1 stores
  __syncthreads();
  if (threadIdx.x == 0) {
    __hip_atomic_fetch_add(f, 1, __ATOMIC_RELEASE, __HIP_MEMORY_SCOPE_AGENT);
    while (__hip_atomic_load(f, __ATOMIC_RELAXED, __HIP_MEMORY_SCOPE_AGENT) < 16) {}
  }
  __syncthreads();
}

// Stage one K128 tile of a 64-row activation panel: 4 agent-scope b64 loads /
// thread (16 KB total). At layout: [ks8 0..15][m 0..63][8] bf16.
__device__ __forceinline__ void load_slots(ull* sreg, const ull* src, int ld8,
                                           int col8, int row0, int t) {
#pragma unroll
  for (int i = 0; i < 4; ++i) {
    int s = t + i * 512;
    int ks = s >> 7, m = (s >> 1) & 63, jh = s & 1;
    sreg[i] = __hip_atomic_load(&src[(size_t)(row0 + m) * ld8 + col8 + ks * 2 + jh],
                                __ATOMIC_RELAXED, __HIP_MEMORY_SCOPE_AGENT);
  }
}
__device__ __forceinline__ void store_slots(short* dst, const ull* sreg, int t) {
#pragma unroll
  for (int i = 0; i < 4; ++i) {
    int s = t + i * 512;
    int ks = s >> 7, m = (s >> 1) & 63, jh = s & 1;
    *(ull*)&dst[(ks * 64 + m) * 8 + jh * 4] = sreg[i];
  }
}

// LSTM cell phase: gates = [A|B panels] @ Wblk^T + bias; c in regs; h -> sc1.
// Waves: (gate = w>>1, m-half = w&1). K128 tiles, double-buffered LDS.
template <int NT, int TA>
__device__ __forceinline__ void cell_phase(
    short (*At)[8192], float* gbuf,
    const ull* srcA, int ldA8, const ull* srcB, int ldB8,
    const short* __restrict__ wblk, const float* __restrict__ bias,
    float* cr, ull* hout, int row0, int j0)
{
  const int t = threadIdx.x;
  const int w = t >> 6, l = t & 63;
  const int gq = w >> 1, mh = w & 1;
  const int ln = l & 31, kh = l >> 5;
  f32x16 acc = zero16();
  ull sreg[4];
  load_slots(sreg, srcA, ldA8, 0, row0, t);
  store_slots(At[0], sreg, t);
  __syncthreads();
#pragma unroll
  for (int tau = 0; tau < NT; ++tau) {
    if (tau + 1 < NT) {
      if (tau + 1 < TA) load_slots(sreg, srcA, ldA8, (tau + 1) * 32, row0, t);
      else              load_slots(sreg, srcB, ldB8, (tau + 1 - TA) * 32, row0, t);
    }
    const short* at = At[tau & 1];
#pragma unroll
    for (int s = 0; s < 8; ++s) {
      bf16x8 a = *(const bf16x8*)&at[((s * 2 + kh) * 64 + mh * 32 + ln) * 8];
      bf16x8 b = *(const bf16x8*)&wblk[(((tau * 8 + s) * 4 + gq) * 64 + l) * 8];
      acc = mfma_bf16(a, b, acc);
    }
    if (tau + 1 < NT) store_slots(At[(tau + 1) & 1], sreg, t);
    __syncthreads();
  }
  // C layout: col = lane&31, row = (r&3)+8*(r>>2)+4*(lane>>5)
#pragma unroll
  for (int r = 0; r < 16; ++r) {
    int mloc = (r & 3) + 8 * (r >> 2) + 4 * kh + mh * 32;
    gbuf[(gq * 64 + mloc) * 32 + ln] = acc[r];
  }
  __syncthreads();
  const int m = t >> 3, nb = (t & 7) * 4;
  short hh[4];
#pragma unroll
  for (int u = 0; u < 4; ++u) {
    int n = nb + u, jn = j0 + n;
    float gi = gbuf[(0 * 64 + m) * 32 + n] + bias[jn];
    float gf = gbuf[(1 * 64 + m) * 32 + n] + bias[512 + jn];
    float gg = gbuf[(2 * 64 + m) * 32 + n] + bias[1024 + jn];
    float go = gbuf[(3 * 64 + m) * 32 + n] + bias[1536 + jn];
    float cn = sigm(gf) * cr[u] + sigm(gi) * tanh_fast(gg);
    cr[u] = cn;
    hh[u] = f2bf(sigm(go) * tanh_fast(cn));
  }
  ull hv; __builtin_memcpy(&hv, hh, 8);
  __hip_atomic_store(&hout[((size_t)(row0 + m) * 512 + j0 + nb) >> 2], hv,
                     __ATOMIC_RELAXED, __HIP_MEMORY_SCOPE_AGENT);
}

// Projection partials (fc or lin): waves (kq = w>>1, mh = w&1) accumulate K32
// slices per K128 chunk; 4 K-partials land in gbuf[kq][m][n] for combine.
template <int NQ>
__device__ __forceinline__ void proj_partials(
    short (*At)[8192], float* gbuf,
    const ull* src, int ld8, const short* __restrict__ wblk, int row0)
{
  const int t = threadIdx.x;
  const int w = t >> 6, l = t & 63;
  const int kq = w >> 1, mh = w & 1;
  const int ln = l & 31, kh = l >> 5;
  f32x16 acc = zero16();
  ull sreg[4];
#pragma unroll
  for (int q = 0; q < NQ; ++q) {
    __syncthreads();
    load_slots(sreg, src, ld8, q * 32, row0, t);
    store_slots(At[0], sreg, t);
    __syncthreads();
#pragma unroll
    for (int sl = 0; sl < 2; ++sl) {
      int s16 = kq * 2 + sl;
      bf16x8 a = *(const bf16x8*)&At[0][((s16 * 2 + kh) * 64 + mh * 32 + ln) * 8];
      bf16x8 b = *(const bf16x8*)&wblk[((q * 8 + s16) * 64 + l) * 8];
      acc = mfma_bf16(a, b, acc);
    }
  }
  __syncthreads();
#pragma unroll
  for (int r = 0; r < 16; ++r) {
    int mloc = (r & 3) + 8 * (r >> 2) + 4 * kh + mh * 32;
    gbuf[(kq * 64 + mloc) * 32 + ln] = acc[r];
  }
  __syncthreads();
}

__global__ __launch_bounds__(512, 2) void decoder_persist(
    const short* __restrict__ wsw0, const short* __restrict__ wsw1,
    const short* __restrict__ fcWsw, const short* __restrict__ linWsw,
    const float* __restrict__ bias0, const float* __restrict__ bias1,
    const float* __restrict__ fcb, const float* __restrict__ linb,
    const float* __restrict__ c0in,
    ull* h0x, ull* h0y, ull* h1x, ull* h1y, ull* zx, ull* zy,
    int* flags, float* __restrict__ outp)
{
  __shared__ __align__(16) short At[2][8192];   // 2 x 16 KB K128 tiles
  __shared__ __align__(16) float gbuf[8192];    // 32 KB gate/partial buffer

  const int x = blockIdx.x;
  const int xcd = x & 7, rr = x >> 3;
  const int g = rr & 15, jhi = rr >> 4;
  const int j = jhi * 8 + xcd;        // j-tile: same j -> same XCD (L2 affinity)
  const int row0 = g * 64, j0 = j * 32;
  int* fl = flags + g * 384;
  const short* wblk0 = wsw0 + j * 98304;
  const short* wblk1 = wsw1 + j * 131072;
  ull* h0buf[2] = {h0x, h0y};
  ull* h1buf[2] = {h1x, h1y};
  ull* zbuf[2] = {zx, zy};

  // c-state in registers for the whole run
  float c0r[4], c1r[4];
  {
    const int m = threadIdx.x >> 3, nb = (threadIdx.x & 7) * 4;
#pragma unroll
    for (int u = 0; u < 4; ++u) {
      c0r[u] = c0in[(size_t)(row0 + m) * 512 + j0 + nb + u];
      c1r[u] = c0in[524288 + (size_t)(row0 + m) * 512 + j0 + nb + u];
    }
  }

  int pc = 0;
#pragma unroll 1
  for (int t = 0; t < 128; ++t) {
    const int p = t & 1;
    // P1: cell0  (K = [z 256 | h0 512])
    cell_phase<6, 2>(At, gbuf, zbuf[p ^ 1], 64, h0buf[p], 128,
                     wblk0, bias0, c0r, h0buf[p ^ 1], row0, j0);
    group_barrier(fl + pc++);
    // P2: cell1  (K = [h0_new 512 | h1 512])
    cell_phase<8, 4>(At, gbuf, h0buf[p ^ 1], 128, h1buf[p], 128,
                     wblk1, bias1, c1r, h1buf[p ^ 1], row0, j0);
    group_barrier(fl + pc++);
    // M3: blocks 0-7 -> z(t) = fc(h1); blocks 8-15 -> out(t-1) = lin(z(t-1))
    if (j < 8) {
      proj_partials<4>(At, gbuf, h1buf[p ^ 1], 128, fcWsw + j * 16384, row0);
      const int m = threadIdx.x >> 3, nb = (threadIdx.x & 7) * 4;
      const int n0 = j * 32;
      short zz[4];
#pragma unroll
      for (int u = 0; u < 4; ++u) {
        int n = nb + u;
        float v = gbuf[(0 * 64 + m) * 32 + n] + gbuf[(1 * 64 + m) * 32 + n] +
                  gbuf[(2 * 64 + m) * 32 + n] + gbuf[(3 * 64 + m) * 32 + n] +
                  fcb[n0 + n];
        zz[u] = f2bf(v);
      }
      ull zv; __builtin_memcpy(&zv, zz, 8);
      __hip_atomic_store(&zbuf[p][((size_t)(row0 + m) * 256 + n0 + nb) >> 2], zv,
                         __ATOMIC_RELAXED, __HIP_MEMORY_SCOPE_AGENT);
    } else if (t > 0) {
      proj_partials<2>(At, gbuf, zbuf[p ^ 1], 64, linWsw + (j - 8) * 8192, row0);
      const int m = threadIdx.x >> 3, nb = (threadIdx.x & 7) * 4;
      const int n0 = (j - 8) * 32;
      float4 ov;
      float* po = &ov.x;
#pragma unroll
      for (int u = 0; u < 4; ++u) {
        int n = nb + u;
        po[u] = gbuf[(0 * 64 + m) * 32 + n] + gbuf[(1 * 64 + m) * 32 + n] +
                gbuf[(2 * 64 + m) * 32 + n] + gbuf[(3 * 64 + m) * 32 + n] +
                linb[n0 + n];
      }
      *(float4*)&outp[(size_t)(t - 1) * 262144 + (size_t)(row0 + m) * 256 + n0 + nb] = ov;
    }
    group_barrier(fl + pc++);
  }
  // final out(127) from z(127) in zbuf[1]
  if (j >= 8) {
    proj_partials<2>(At, gbuf, zbuf[1], 64, linWsw + (j - 8) * 8192, row0);
    const int m = threadIdx.x >> 3, nb = (threadIdx.x & 7) * 4;
    const int n0 = (j - 8) * 32;
    float4 ov;
    float* po = &ov.x;
#pragma unroll
    for (int u = 0; u < 4; ++u) {
      int n = nb + u;
      po[u] = gbuf[(0 * 64 + m) * 32 + n] + gbuf[(1 * 64 + m) * 32 + n] +
              gbuf[(2 * 64 + m) * 32 + n] + gbuf[(3 * 64 + m) * 32 + n] +
              linb[n0 + n];
    }
    *(float4*)&outp[(size_t)127 * 262144 + (size_t)(row0 + m) * 256 + n0 + nb] = ov;
  }
}

// ---------------------------------------------------------------------------
extern "C" void kernel_launch(void* const* d_in, const int* in_sizes, int n_in,
                              void* d_out, int out_size, void* d_ws, size_t ws_size,
                              hipStream_t stream) {
  const float* z0   = (const float*)d_in[0];
  const float* h0in = (const float*)d_in[1];
  const float* c0in = (const float*)d_in[2];
  const float* Wih0 = (const float*)d_in[3];
  const float* Whh0 = (const float*)d_in[4];
  const float* bih0 = (const float*)d_in[5];
  const float* bhh0 = (const float*)d_in[6];
  const float* Wih1 = (const float*)d_in[7];
  const float* Whh1 = (const float*)d_in[8];
  const float* bih1 = (const float*)d_in[9];
  const float* bhh1 = (const float*)d_in[10];
  const float* fcW  = (const float*)d_in[11];
  const float* fcb  = (const float*)d_in[12];
  const float* linW = (const float*)d_in[13];
  const float* linb = (const float*)d_in[14];
  float* out = (float*)d_out;

  char* ws = (char*)d_ws;
  short* wsw0  = (short*)(ws + 0);         // 3,145,728 B
  short* wsw1  = (short*)(ws + 3145728);   // 4,194,304 B
  short* fcWsw = (short*)(ws + 7340032);   //   262,144 B
  short* linWsw= (short*)(ws + 7602176);   //   131,072 B
  float* bias0 = (float*)(ws + 7733248);   //     8,192 B
  float* bias1 = (float*)(ws + 7741440);   //     8,192 B
  short* zb0   = (short*)(ws + 7749632);   //   524,288 B
  short* zb1   = (short*)(ws + 8273920);   //   524,288 B
  short* h0b0  = (short*)(ws + 8798208);   // 1,048,576 B
  short* h0b1  = (short*)(ws + 9846784);
  short* h1b0  = (short*)(ws + 10895360);
  short* h1b1  = (short*)(ws + 11943936);
  int*   flags = (int*)  (ws + 12992512);  //    24,576 B  (total 13,017,088)

  prep_kernel<<<20264, 256, 0, stream>>>(z0, h0in, Wih0, Whh0, bih0, bhh0,
                                         Wih1, Whh1, bih1, bhh1, fcW, linW,
                                         wsw0, wsw1, fcWsw, linWsw, bias0, bias1,
                                         zb1, h0b0, h1b0, flags);

  decoder_persist<<<256, 512, 0, stream>>>(
      wsw0, wsw1, fcWsw, linWsw, bias0, bias1, fcb, linb, c0in,
      (ull*)h0b0, (ull*)h0b1, (ull*)h1b0, (ull*)h1b1, (ull*)zb0, (ull*)zb1,
      flags, out);
}